// Round 14
// baseline (225.643 us; speedup 1.0000x reference)
//
#include <hip/hip_runtime.h>
#include <hip/hip_bf16.h>

// CIN forward: 3 chained GEMMs M=16384, N=256, K={1600,5120,5120}, bf16 MFMA.
// A rows are outer products h_r (x) x_r formed in registers.
// Global K-permutation: k' = s*32 + q*8 + j  <->  f = 4*(s%SPW)+q, g = 8*(s/SPW)+j
// applied identically to A-formation and the pre-fragmented W blob (layout-immune).
// R14 = R13 with the prologue W-staging fix (r*512, NOT r*1024: R13 left
// slots 2,3 unstaged -> Inf). Structure: 512-thread / 8-wave blocks, wave
// tile 16x64 -> 4 waves/SIMD; pkrne pack; 8-slot pipeline, phase=2 K-steps,
// 1 stage-instr/thread/phase, counted vmcnt(1), raw s_barrier.
// Epilogue: cross-wave (wv^1) d-sum via LDS overlay on xs (post-barrier).

typedef __attribute__((ext_vector_type(8))) short short8;
typedef __attribute__((ext_vector_type(4))) float f32x4;

#define DEVINL __device__ __forceinline__

DEVINL float bf16f(unsigned short u) {
  return __builtin_bit_cast(float, ((unsigned int)u) << 16);
}
DEVINL unsigned short f2bf(float f) {
  unsigned int u = __builtin_bit_cast(unsigned int, f);
  u = u + 0x7FFFu + ((u >> 16) & 1u);
  return (unsigned short)(u >> 16);
}
DEVINL unsigned int pk2(float lo, float hi) {
  union { __hip_bfloat162 h; unsigned int u; } cv;
  cv.h = __float22bfloat162_rn(make_float2(lo, hi));
  return cv.u;
}
// RNE f32->bf16 pair pack, no NaN handling (data is NaN-free). Bit-identical
// to __float22bfloat162_rn for finite values; ~half the instructions.
DEVINL unsigned int pkrne(float a, float b) {
  unsigned int ua = __builtin_bit_cast(unsigned int, a);
  unsigned int ub = __builtin_bit_cast(unsigned int, b);
  ua = ua + 0x7FFFu + ((ua >> 16) & 1u);
  ub = ub + 0x7FFFu + ((ub >> 16) & 1u);
  return (ua >> 16) | (ub & 0xFFFF0000u);
}
DEVINL void gl_lds16(const unsigned short* g, unsigned short* l) {
  __builtin_amdgcn_global_load_lds(
      (const __attribute__((address_space(1))) unsigned int*)g,
      (__attribute__((address_space(3))) unsigned int*)l, 16, 0, 0);
}

// ---------------- prep: x transpose  in[b][g][d] f32 -> xT[(b*32+d)][g] bf16
__global__ void prep_x(const float* __restrict__ in, unsigned short* __restrict__ xT) {
  __shared__ float lf[40 * 33];
  const int b = blockIdx.x, t = threadIdx.x;
  for (int i = t; i < 1280; i += 256) {
    int g = i >> 5, d = i & 31;
    lf[g * 33 + d] = in[b * 1280 + i];
  }
  __syncthreads();
  for (int i = t; i < 1280; i += 256) {
    int d = i / 40, g = i % 40;
    xT[b * 1280 + i] = f2bf(lf[g * 33 + d]);
  }
}

// ---------------- prep: fragment weights with the global K-permutation.
// blob: [s][grp 0..15][lane 0..63][j 0..7], value = W[f*40+g][grp*16+(lane&15)]
// with f = 4*(s%SPW) + (lane>>4), g = 8*(s/SPW) + j.
__global__ void prep_w(const float* __restrict__ W1, const float* __restrict__ W2,
                       const float* __restrict__ W3, unsigned short* __restrict__ Wf1,
                       unsigned short* __restrict__ Wf2, unsigned short* __restrict__ Wf3) {
  __shared__ float lw[8192];
  const int bid = blockIdx.x, t = threadIdx.x;
  const float* W; unsigned short* dst; int s, SPW;
  if (bid < 50)       { W = W1; dst = Wf1; s = bid;       SPW = 10; }
  else if (bid < 210) { W = W2; dst = Wf2; s = bid - 50;  SPW = 32; }
  else                { W = W3; dst = Wf3; s = bid - 210; SPW = 32; }
  const int smod = s % SPW, w = s / SPW;
  for (int i = t; i < 8192; i += 256) {
    int kl = i >> 8, col = i & 255;
    int f = 4 * smod + (kl >> 3);
    int g = 8 * w + (kl & 7);
    lw[i] = W[(f * 40 + g) * 256 + col];
  }
  __syncthreads();
  for (int c = t; c < 1024; c += 256) {
    int grp = c >> 6, ll = c & 63;
    int qq = ll >> 4, col = grp * 16 + (ll & 15);
    unsigned short u[8];
#pragma unroll
    for (int j = 0; j < 8; ++j) u[j] = f2bf(lw[(qq * 8 + j) * 256 + col]);
    uint4 v;
    v.x = (unsigned)u[0] | ((unsigned)u[1] << 16);
    v.y = (unsigned)u[2] | ((unsigned)u[3] << 16);
    v.z = (unsigned)u[4] | ((unsigned)u[5] << 16);
    v.w = (unsigned)u[6] | ((unsigned)u[7] << 16);
    *(uint4*)&dst[s * 8192 + c * 8] = v;
  }
}

// ---------------- main layer kernel
// grid 512: blockIdx = bm*4 + tn.  BM=128 rows, BN=64 cols. 512 threads,
// 8 waves, wave tile 16x64 (mi=1, n-iters=4), 16x16x32 bf16 MFMA.
template <int LAYER>
__global__ __launch_bounds__(512, 4) void cin_layer(
    const unsigned short* __restrict__ Wfrag, const unsigned short* __restrict__ xT,
    const unsigned short* __restrict__ hIn, const float* __restrict__ bias,
    unsigned short* __restrict__ hOut, float* __restrict__ out) {
  constexpr int FIN = (LAYER == 1) ? 40 : 128;
  constexpr int NKT = FIN * 40 / 32;   // 50 / 160
  constexpr int SPW = FIN / 4;         // 10 / 32 (steps per g-window); even
  constexpr int HP = 144;              // h row pitch (shorts)

  // LDS: Bb[8][2048] eight-slot B pipeline | xs[128][40] | (L>1) hs[128 f][HP]
  constexpr int SM_SHORTS = 16384 + 5120 + ((LAYER > 1) ? 128 * HP : 8);
  __shared__ __align__(16) unsigned short smem[SM_SHORTS];
  unsigned short* Bb = smem;
  unsigned short* xs = smem + 16384;
  unsigned short* hs = smem + 16384 + 5120;

  const int tid = threadIdx.x;
  const int l = tid & 63;
  const int wv = tid >> 6;             // wave 0..7
  const int q = l >> 4;
  const int bm = blockIdx.x >> 2;
  const int tn = blockIdx.x & 3;
  const int r0 = bm * 128;
  const int b0 = bm * 4;

  // staging thread roles (512 threads = 2 slots x 256 threads)
  const int sel = tid >> 8;            // 0/1: which of the 2 staged slots
  const int idx = tid & 255;           // position within slot (x8 shorts)

  // ---- prologue staging (all global_load_lds, fully drained at syncthreads)
  // steps 0..3 -> slots 0..3 (16KB = 2 rounds of 512 threads x 16B)
#pragma unroll
  for (int r = 0; r < 2; ++r) {
    const int i2 = r * 512 + tid;      // 0..1023 -> slots 0..3 (R13 bug: r*1024)
    const int sl = i2 >> 8;
    gl_lds16(Wfrag + sl * 8192 + tn * 2048 + (i2 & 255) * 8, Bb + i2 * 8);
  }
  // xs = 5120 shorts = 1.25 rounds
  gl_lds16(xT + r0 * 40 + tid * 8, xs + tid * 8);
  if (tid < 128)
    gl_lds16(xT + r0 * 40 + 4096 + tid * 8, xs + 4096 + tid * 8);
  if constexpr (LAYER > 1) {
    const unsigned short* hsrc = hIn + bm * (128 * HP);
#pragma unroll
    for (int i = 0; i < 4; ++i)        // 4 x 8KB
      gl_lds16(hsrc + i * 4096 + tid * 8, hs + i * 4096 + tid * 8);
    if (tid < 256)                     // final 4KB -> 36864B total exactly
      gl_lds16(hsrc + 16384 + tid * 8, hs + 16384 + tid * 8);
  }

  f32x4 acc[4];
#pragma unroll
  for (int n = 0; n < 4; ++n) acc[n] = f32x4{0.f, 0.f, 0.f, 0.f};

  const int rl0 = wv * 16 + (l & 15);  // this wave's row

  __syncthreads();   // full drain once (prologue loads + barrier)

#pragma unroll
  for (int w = 0; w < 5; ++w) {
    // expand this g-window of x to f32 registers (static indices)
    float xw[8];
    {
      short8 xv = *(const short8*)&xs[rl0 * 40 + w * 8];
#pragma unroll
      for (int d = 0; d < 4; ++d) {
        unsigned int uu = ((const unsigned int*)&xv)[d];
        xw[2 * d]     = __builtin_bit_cast(float, uu << 16);
        xw[2 * d + 1] = __builtin_bit_cast(float, uu & 0xffff0000u);
      }
    }

    for (int sp = 0; sp < SPW / 2; ++sp) {
      const int s0 = w * SPW + 2 * sp;     // phase covers steps s0, s0+1
      __builtin_amdgcn_sched_barrier(0);
      asm volatile("s_waitcnt vmcnt(1)" ::: "memory");
      __builtin_amdgcn_s_barrier();
      __builtin_amdgcn_sched_barrier(0);

      // stage steps s0+4 (threads 0-255) and s0+5 (threads 256-511):
      // exactly ONE gl_lds per thread per phase -> vmcnt counts phases.
      {
        const int stp = s0 + 4 + sel;
        const int stc = (stp < NKT) ? stp : (NKT - 1);   // clamped tail
        gl_lds16(Wfrag + stc * 8192 + tn * 2048 + idx * 8,
                 Bb + (stp & 7) * 2048 + idx * 8);
      }

      // two K-steps, no barrier between them
#pragma unroll
      for (int half = 0; half < 2; ++half) {
        const int s = s0 + half;
        const int sm = 2 * sp + half;
        const unsigned short* bb = Bb + (s & 7) * 2048 + l * 8;
        short8 bfr[4];
#pragma unroll
        for (int n = 0; n < 4; ++n)
          bfr[n] = *(const short8*)(bb + n * 512);

        const int f = 4 * sm + q;
        const float hf = (LAYER == 1) ? bf16f(xs[rl0 * 40 + f])
                                      : bf16f(hs[f * HP + rl0]);
        union { unsigned int u[4]; short8 s8; } A;
#pragma unroll
        for (int jj = 0; jj < 4; ++jj)
          A.u[jj] = pkrne(hf * xw[2 * jj], hf * xw[2 * jj + 1]);
#pragma unroll
        for (int n = 0; n < 4; ++n)
          acc[n] = __builtin_amdgcn_mfma_f32_16x16x32_bf16(
              A.s8, bfr[n], acc[n], 0, 0, 0);
      }
    }
  }
  asm volatile("s_waitcnt vmcnt(0)" ::: "memory");

  // ---- epilogue (branch is block-uniform: tn is per-block)
  const int colb = tn * 64;
  float bv[4];
#pragma unroll
  for (int n = 0; n < 4; ++n) bv[n] = bias[colb + n * 16 + (l & 15)];

  if (LAYER == 3 || tn < 2) {
    const int jb = (LAYER == 1) ? 0 : (LAYER == 2) ? 128 : 256;
    // per-wave partial d-sum (16 rows); wave wv covers b = b0+(wv>>1),
    // d-half = wv&1. Pair (wv, wv^1) completes the 32-d sum via LDS.
    float psum[4];
#pragma unroll
    for (int n = 0; n < 4; ++n) {
      float s = 0.f;
#pragma unroll
      for (int r = 0; r < 4; ++r) s += fmaxf(acc[n][r] + bv[n], 0.f);
      s += __shfl_xor(s, 16);
      s += __shfl_xor(s, 32);
      psum[n] = s;
    }
    __syncthreads();                       // xs reads done -> safe to reuse
    float* sred = (float*)xs;              // [pair 0..3][n 0..3][col 0..15]
    if (wv & 1) {
      if (l < 16)
#pragma unroll
        for (int n = 0; n < 4; ++n)
          sred[((wv >> 1) * 4 + n) * 16 + l] = psum[n];
    }
    __syncthreads();
    if (!(wv & 1) && l < 16) {
#pragma unroll
      for (int n = 0; n < 4; ++n) {
        float tot = psum[n] + sred[((wv >> 1) * 4 + n) * 16 + l];
        out[(b0 + (wv >> 1)) * 512 + jb + colb + n * 16 + l] = tot;
      }
    }
  } else {
    // h half: cols 128..255 -> hOut[bm][f][rl], pitch 144
#pragma unroll
    for (int n = 0; n < 4; ++n) {
      const int ff = (tn - 2) * 64 + n * 16 + (l & 15);
      const int rl = wv * 16 + (l >> 4) * 4;
      float v0 = fmaxf(acc[n][0] + bv[n], 0.f);
      float v1 = fmaxf(acc[n][1] + bv[n], 0.f);
      float v2 = fmaxf(acc[n][2] + bv[n], 0.f);
      float v3 = fmaxf(acc[n][3] + bv[n], 0.f);
      uint2 pv;
      pv.x = pk2(v0, v1);
      pv.y = pk2(v2, v3);
      *(uint2*)&hOut[bm * (128 * HP) + ff * HP + rl] = pv;
    }
  }
}

extern "C" void kernel_launch(void* const* d_in, const int* in_sizes, int n_in,
                              void* d_out, int out_size, void* d_ws, size_t ws_size,
                              hipStream_t stream) {
  (void)in_sizes; (void)n_in; (void)out_size; (void)ws_size;
  const float* in = (const float*)d_in[0];
  const float* W1 = (const float*)d_in[1];
  const float* b1 = (const float*)d_in[2];
  const float* W2 = (const float*)d_in[3];
  const float* b2 = (const float*)d_in[4];
  const float* W3 = (const float*)d_in[5];
  const float* b3 = (const float*)d_in[6];
  float* out = (float*)d_out;
  char* ws = (char*)d_ws;

  unsigned short* xT  = (unsigned short*)(ws);                 // 1,310,720 B
  unsigned short* Wf1 = (unsigned short*)(ws + 1310720);       //   819,200 B
  unsigned short* Wf2 = (unsigned short*)(ws + 2129920);       // 2,621,440 B
  unsigned short* Wf3 = (unsigned short*)(ws + 4751360);       // 2,621,440 B
  unsigned short* h1  = (unsigned short*)(ws + 7372800);       // 4,718,592 B
  unsigned short* h2  = (unsigned short*)(ws + 12091392);      // 4,718,592 B

  prep_x<<<dim3(512), dim3(256), 0, stream>>>(in, xT);
  prep_w<<<dim3(370), dim3(256), 0, stream>>>(W1, W2, W3, Wf1, Wf2, Wf3);
  cin_layer<1><<<dim3(512), dim3(512), 0, stream>>>(Wf1, xT, (const unsigned short*)nullptr, b1, h1, out);
  cin_layer<2><<<dim3(512), dim3(512), 0, stream>>>(Wf2, xT, h1, b2, h2, out);
  cin_layer<3><<<dim3(512), dim3(512), 0, stream>>>(Wf3, xT, h2, b3, (unsigned short*)nullptr, out);
}